// Round 11
// baseline (280.068 us; speedup 1.0000x reference)
//
#include <hip/hip_runtime.h>
#include <math.h>

#define IMG 416
#define N_ANG 320
#define N_DET 416
#define N_SAMP 416

// ---------------------------------------------------------------------------
// Padded global fp8 image G: stride 464 B, 432 rows. Pixel (r,c) of the diff
// image lives at G[(r+8)*464 + (c+8)], zero outside [0,416)^2.
// ---------------------------------------------------------------------------
#define GSTRIDE 464
#define GROWS   432
#define GBYTES  ((size_t)GROWS * GSTRIDE)        // 200448
#define GWORDS  (GROWS * GSTRIDE / 4)            // 50112

#define SPLANE  (N_ANG * N_DET)                  // 133120 rays
#define S1BYTES ((size_t)SPLANE * 4)             // one plane (atomicAdd target)
#define WSNEED  (GBYTES + S1BYTES + 64)

// LDS staged quadrant: 229 rows x 59 dwords (236 B row stride). 59 % 32 = 27,
// coprime with 32 banks -> row-strided lane fronts spread across ALL banks at
// 2 lanes/bank (free). 229 = 227 needed + 2 guard rows for the ~1e-2 px
// incremental-march drift (guards hold valid zero-pad data, not stale LDS).
#define LSTRIDE_W 59
#define LSTRIDE_B (LSTRIDE_W * 4)                // 236
#define LROWS     229
#define LWORDS    (LROWS * LSTRIDE_W)            // 13511 dwords = 54044 B -> 3 blk/CU

#define NBLK (N_ANG * 4)                         // 1280 proj blocks

typedef float vfloat2 __attribute__((ext_vector_type(2)));

// ---------------------------------------------------------------------------
// Kernel A: build padded fp8 diff image; zero S plane, counter, d_out.
// ---------------------------------------------------------------------------
__global__ __launch_bounds__(256) void pack_kernel(const float* __restrict__ a,
                                                   const float* __restrict__ b,
                                                   unsigned int* __restrict__ G,
                                                   float* __restrict__ S,
                                                   unsigned int* __restrict__ cnt,
                                                   float* __restrict__ out) {
    int i = blockIdx.x * 256 + threadIdx.x;
    if (i == 0) { out[0] = 0.0f; *cnt = 0u; }
    if (i < SPLANE) S[i] = 0.0f;
    if (i >= GWORDS) return;
    int pr = i / (GSTRIDE / 4);            // 116 words per padded row
    int wc = i - pr * (GSTRIDE / 4);
    int r  = pr - 8;
    int c0 = wc * 4 - 8;
    float v[4];
    #pragma unroll
    for (int j = 0; j < 4; ++j) {
        int c = c0 + j;
        float val = 0.0f;
        if ((unsigned)r < (unsigned)IMG && (unsigned)c < (unsigned)IMG) {
            int idx = r * IMG + c;
            val = a[idx] - b[idx];
        }
        v[j] = val;
    }
    unsigned int u = __builtin_amdgcn_cvt_pk_fp8_f32(v[0], v[1], 0u, false);
    u = __builtin_amdgcn_cvt_pk_fp8_f32(v[2], v[3], u, true);
    G[i] = u;
}

__global__ void zero_out_kernel(float* __restrict__ out) {
    if (threadIdx.x == 0) out[0] = 0.0f;
}

// ---------------------------------------------------------------------------
// Kernel B: block = (angle, quadrant), thread = detector. Stage the quadrant
// (+2 guard rows) into LDS (1 B/px, 236 B stride), march the ray's exact
// sample range in the quadrant's half-open ownership box: 4x ds_read_u8 +
// 2x HW fp8 unpack per sample. Ray partials atomicAdd into one S plane; the
// LAST block to finish squares+sums S and writes the final loss (no third
// dispatch).
// ---------------------------------------------------------------------------
__global__ __launch_bounds__(448) void proj_lds(const unsigned int* __restrict__ G,
                                                float* __restrict__ S,
                                                unsigned int* __restrict__ cnt,
                                                float* __restrict__ out,
                                                float theta_step, float gmax,
                                                float gstep, float t0,
                                                float dtstep, float coef) {
    __shared__ unsigned int Lw[LWORDS];
    __shared__ float wsum[7];
    __shared__ int lastFlag;

    const int blk = blockIdx.x;          // 0..1279
    const int a  = blk >> 2;
    const int q  = blk & 3;
    const int qi = q >> 1, qj = q & 1;
    const int r0 = qi ? 222 : -2;        // first staged pixel row
    const int c0 = qj ? 220 : -4;        // first staged pixel col
    const int nrows = (qi ? 197 : 227) + 2;   // +2 guard rows (valid G data)

    // --- cooperative stage: nrows x 59 dwords (word-aligned in G) ----------
    // Max G row touched: qi=0: 6+228=234; qi=1: 230+198=428  (< 432, valid).
    {
        const int gbase = ((r0 + 8) * GSTRIDE + (c0 + 8)) >> 2;  // word index
        const int total = nrows * LSTRIDE_W;
        for (int i = threadIdx.x; i < total; i += 448) {
            int rr = i / LSTRIDE_W;
            int cc = i - rr * LSTRIDE_W;
            Lw[rr * LSTRIDE_W + cc] = G[gbase + rr * 116 + cc];
        }
    }
    __syncthreads();

    const int d = threadIdx.x;
    if (d < N_DET) {
        const float theta = (float)a * theta_step;
        const float gamma = fmaf((float)d, gstep, -gmax);
        float s1, c1, s2, c2;
        sincosf(theta, &s1, &c1);
        sincosf(theta + gamma, &s2, &c2);
        const float sx = fmaf(1075.0f, c1, 207.5f);
        const float sy = fmaf(1075.0f, s1, 207.5f);

        // col(k) = C0 - k*dc ; row(k) = R0 - k*dr   (k = 0..415)
        const float C0 = fmaf(-t0, c2, sx), dc = dtstep * c2;
        const float R0 = fmaf(-t0, s2, sy), dr = dtstep * s2;

        // ownership box, half-open; support of nonzero taps is [-1,416).
        // Shared inner boundaries use identical fp expressions in both
        // neighboring quadrants -> exact partition of each ray's samples.
        const float cl = qj ? 224.0f : -1.0f, ch = qj ? 416.0f : 224.0f;
        const float rl = qi ? 224.0f : -1.0f, rh = qi ? 416.0f : 224.0f;

        int klo = 0, khi = N_SAMP - 1;
        auto clip1 = [&](float X0, float dX, float lo, float hi) {
            if (fabsf(dX) < 1e-8f) {
                if (!(X0 >= lo && X0 < hi)) { klo = 1; khi = 0; }
            } else {
                const float inv = 1.0f / dX;
                float x1 = (X0 - hi) * inv;        // strict side
                float x2 = (X0 - lo) * inv;        // inclusive side
                x1 = fminf(fmaxf(x1, -1e6f), 1e6f);
                x2 = fminf(fmaxf(x2, -1e6f), 1e6f);
                int lo_k, hi_k;
                if (dX > 0.0f) { lo_k = (int)floorf(x1) + 1; hi_k = (int)floorf(x2); }
                else           { lo_k = (int)ceilf(x2);      hi_k = (int)ceilf(x1) - 1; }
                klo = max(klo, lo_k);
                khi = min(khi, hi_k);
            }
        };
        clip1(C0, dc, cl, ch);
        clip1(R0, dr, rl, rh);

        if (klo <= khi) {
            // LDS-relative coords (>=1 inside the box -> trunc==floor; march
            // drift <1e-2 px is absorbed by guard rows / column slack)
            float colR = fmaf(-(float)klo, dc, C0) - (float)c0;
            float rowR = fmaf(-(float)klo, dr, R0) - (float)r0;
            const unsigned char* __restrict__ Lb = (const unsigned char*)Lw;
            float acc = 0.0f;
            #pragma unroll 4
            for (int k = klo; k <= khi; ++k) {
                const int ci = (int)colR;
                const int ri = (int)rowR;
                const float wc = colR - (float)ci;
                const float wr = rowR - (float)ri;
                const int base = ri * LSTRIDE_B + ci;
                const unsigned int b00 = Lb[base];
                const unsigned int b01 = Lb[base + 1];
                const unsigned int b10 = Lb[base + LSTRIDE_B];
                const unsigned int b11 = Lb[base + LSTRIDE_B + 1];
                const vfloat2 t2 = __builtin_amdgcn_cvt_pk_f32_fp8(b00 | (b01 << 8), false);
                const vfloat2 b2 = __builtin_amdgcn_cvt_pk_f32_fp8(b10 | (b11 << 8), false);
                const float top = fmaf(wc, t2[1] - t2[0], t2[0]);
                const float bot = fmaf(wc, b2[1] - b2[0], b2[0]);
                acc = fmaf(wr, bot - top, acc + top);
                colR -= dc;
                rowR -= dr;
            }
            atomicAdd(&S[a * N_DET + d], acc);   // device-scope, coherent
        }
    }

    // --- last-block-done reduction (classic threadfence pattern) -----------
    __threadfence();                     // make this block's adds visible
    __syncthreads();
    if (threadIdx.x == 0) {
        unsigned int old = __hip_atomic_fetch_add(cnt, 1u, __ATOMIC_ACQ_REL,
                                                  __HIP_MEMORY_SCOPE_AGENT);
        lastFlag = (old == (unsigned)(NBLK - 1));
    }
    __syncthreads();
    if (lastFlag) {
        __threadfence();                 // acquire: invalidate stale lines
        float sq = 0.0f;
        for (int i = threadIdx.x; i < SPLANE; i += 448) {
            const float v = __hip_atomic_load(&S[i], __ATOMIC_RELAXED,
                                              __HIP_MEMORY_SCOPE_AGENT);
            sq = fmaf(v, v, sq);
        }
        #pragma unroll
        for (int m = 32; m > 0; m >>= 1) sq += __shfl_down(sq, m, 64);
        if ((threadIdx.x & 63) == 0) wsum[threadIdx.x >> 6] = sq;
        __syncthreads();
        if (threadIdx.x == 0) {
            float t = 0.0f;
            #pragma unroll
            for (int w = 0; w < 7; ++w) t += wsum[w];
            out[0] = t * coef;
        }
    }
}

// ---------------------------------------------------------------------------
// Fallback (ws too small): fused one-thread-per-ray fp32 gather version.
// ---------------------------------------------------------------------------
__global__ __launch_bounds__(256) void proj_fused(const float* __restrict__ imgA,
                                                  const float* __restrict__ imgB,
                                                  float* __restrict__ out,
                                                  float theta_step, float gmax,
                                                  float gstep, float t0,
                                                  float dtstep, float coef) {
    const int idx = blockIdx.x * 256 + threadIdx.x;
    const int a  = idx / N_DET;
    const int dd = idx - a * N_DET;
    const float theta = (float)a * theta_step;
    const float gamma = fmaf((float)dd, gstep, -gmax);
    float s1, c1, s2, c2;
    sincosf(theta, &s1, &c1);
    sincosf(theta + gamma, &s2, &c2);
    const float sx = 1075.0f * c1 + 207.5f;
    const float sy = 1075.0f * s1 + 207.5f;
    float acc = 0.0f;
    #pragma unroll 4
    for (int s = 0; s < N_SAMP; ++s) {
        const float t   = fmaf((float)s, dtstep, t0);
        const float col = fmaf(-t, c2, sx);
        const float row = fmaf(-t, s2, sy);
        const float c0 = floorf(col);
        const float r0 = floorf(row);
        const float wc = col - c0;
        const float wr = row - r0;
        const int ci = (int)c0;
        const int ri = (int)r0;
        auto Gv = [&](int r, int c) -> float {
            if ((unsigned)r < (unsigned)IMG && (unsigned)c < (unsigned)IMG)
                return imgA[r * IMG + c] - imgB[r * IMG + c];
            return 0.0f;
        };
        const float v00 = Gv(ri, ci);
        const float v01 = Gv(ri, ci + 1);
        const float v10 = Gv(ri + 1, ci);
        const float v11 = Gv(ri + 1, ci + 1);
        const float top = fmaf(wc, v01 - v00, v00);
        const float bot = fmaf(wc, v11 - v10, v10);
        acc += fmaf(wr, bot - top, top);
    }
    float sq = acc * acc;
    #pragma unroll
    for (int o = 32; o > 0; o >>= 1) sq += __shfl_down(sq, o, 64);
    __shared__ float wsum[4];
    const int lane = threadIdx.x & 63;
    if (lane == 0) wsum[threadIdx.x >> 6] = sq;
    __syncthreads();
    if (threadIdx.x == 0)
        atomicAdd(out, (wsum[0] + wsum[1] + wsum[2] + wsum[3]) * coef);
}

extern "C" void kernel_launch(void* const* d_in, const int* in_sizes, int n_in,
                              void* d_out, int out_size, void* d_ws, size_t ws_size,
                              hipStream_t stream) {
    const float* in = (const float*)d_in[0];
    const float* tg = (const float*)d_in[1];
    float* out = (float*)d_out;

    const double half_diag = (IMG / 2.0) * sqrt(2.0);
    const double ray_len   = IMG * sqrt(2.0);
    const float  gmax      = (float)asin(half_diag / 1075.0);
    const float  gstep     = (float)(2.0 * (double)gmax / (N_DET - 1));
    const float  t0        = (float)(1075.0 - ray_len / 2.0);
    const float  dtstep    = (float)(ray_len / (N_SAMP - 1));
    const float  theta_step = (float)(2.0 * M_PI / N_ANG);
    const double dt        = ray_len / (N_SAMP - 1);
    const double SCALE     = 512.0 / 416.0 * 0.03;
    const float  coef      = (float)(dt * dt * SCALE / ((double)N_ANG * N_DET));

    if (ws_size >= WSNEED) {
        unsigned int* G = (unsigned int*)d_ws;
        float* S = (float*)((char*)d_ws + GBYTES);
        unsigned int* cnt = (unsigned int*)((char*)d_ws + GBYTES + S1BYTES);
        // grid covers max(GWORDS, SPLANE) for table build + S/cnt/out zeroing
        pack_kernel<<<(SPLANE + 255) / 256, 256, 0, stream>>>(in, tg, G, S, cnt, out);
        proj_lds<<<NBLK, 448, 0, stream>>>(G, S, cnt, out, theta_step, gmax,
                                           gstep, t0, dtstep, coef);
    } else {
        zero_out_kernel<<<1, 64, 0, stream>>>(out);
        proj_fused<<<(N_ANG * N_DET) / 256, 256, 0, stream>>>(
            in, tg, out, theta_step, gmax, gstep, t0, dtstep, coef);
    }
}

// Round 12
// 112.859 us; speedup vs baseline: 2.4816x; 2.4816x over previous
//
#include <hip/hip_runtime.h>
#include <math.h>

#define IMG 416
#define N_ANG 320
#define N_DET 416
#define N_SAMP 416

// ---------------------------------------------------------------------------
// Padded global fp8 PAIR table Gp: entry (pr,pc) = 2 bytes
// {fp8(v(r,c)), fp8(v(r,c+1))}, r=pr-8, c=pc-8, v = zero-padded diff image.
// 432 rows x 432 entries x 2 B, row stride 864 B (216 dwords).
// ---------------------------------------------------------------------------
#define GPROWS   432
#define GPSTRIDE_W 216                   // dwords per row (864 B)
#define GPWORDS  (GPROWS * GPSTRIDE_W)   // 93312 dwords = 373248 B
#define GPBYTES  ((size_t)GPWORDS * 4)

#define SPLANE  (N_ANG * N_DET)          // 133120 rays
#define S1BYTES ((size_t)SPLANE * 4)
#define WSNEED  (GPBYTES + S1BYTES)

// LDS staged tile: 216 rows x 55 dwords (= 110 px-pairs, 220 B row stride).
// 55 % 32 = 23, coprime with 32 banks. 47520 B -> 3 blocks/CU.
#define LSTRIDE_W  55
#define LSTRIDE_PX 110
#define LROWS      216
#define LWORDS     (LROWS * LSTRIDE_W)

#define NBLK (N_ANG * 8)                 // 320 angles x (2 row-halves x 4 col-tiles)

typedef float vfloat2 __attribute__((ext_vector_type(2)));

// ---------------------------------------------------------------------------
// Kernel A: build the fp8 pair table; zero the S plane and d_out.
// ---------------------------------------------------------------------------
__global__ __launch_bounds__(256) void pack_kernel(const float* __restrict__ a,
                                                   const float* __restrict__ b,
                                                   unsigned int* __restrict__ Gp,
                                                   float* __restrict__ S,
                                                   float* __restrict__ out) {
    int i = blockIdx.x * 256 + threadIdx.x;
    if (i == 0) out[0] = 0.0f;
    if (i < SPLANE) S[i] = 0.0f;
    if (i >= GPWORDS) return;
    int row = i / GPSTRIDE_W;
    int wc  = i - row * GPSTRIDE_W;
    int r  = row - 8;
    int c0 = wc * 2 - 8;
    auto D = [&](int rr, int cc) -> float {
        if ((unsigned)rr < (unsigned)IMG && (unsigned)cc < (unsigned)IMG)
            return a[rr * IMG + cc] - b[rr * IMG + cc];
        return 0.0f;
    };
    const float v0 = D(r, c0), v1 = D(r, c0 + 1), v2 = D(r, c0 + 2);
    unsigned int u = __builtin_amdgcn_cvt_pk_fp8_f32(v0, v1, 0u, false);
    u = __builtin_amdgcn_cvt_pk_fp8_f32(v1, v2, u, true);
    Gp[i] = u;
}

__global__ void zero_out_kernel(float* __restrict__ out) {
    if (threadIdx.x == 0) out[0] = 0.0f;
}

// ---------------------------------------------------------------------------
// Kernel B: block = (angle, 1-of-8 tile [2 row-halves x 4 col-tiles]),
// thread = detector. Stage the tile's pair-entries into LDS, then march the
// ray's exact sample range inside the tile's half-open ownership box.
// Per sample: 2x aligned ds_read_u16 + 2x HW fp8 unpack. Partial ray sums
// atomicAdd into one S plane.
// ---------------------------------------------------------------------------
__global__ __launch_bounds__(448) void proj_lds(const unsigned int* __restrict__ Gp,
                                                float* __restrict__ S,
                                                float theta_step, float gmax,
                                                float gstep, float t0,
                                                float dtstep) {
    __shared__ unsigned int Lw[LWORDS];

    const int blk = blockIdx.x;           // 0..2559
    const int a    = blk >> 3;
    const int tile = blk & 7;
    const int qi = tile >> 2, qj = tile & 3;     // row-half, col-quarter
    const int r0s = 208 * qi - 4;         // first staged pixel row
    const int c0s = 104 * qj - 4;         // first staged pair col (even offset)

    // --- cooperative stage: 216 rows x 55 dwords ---------------------------
    // Gp word base: row r0s+8 in [4,212], pair col c0s+8 -> byte (c0s+8)*2,
    // word ((c0s+8)*2)/4 = (104*qj+4)/2 = 52*qj+2  (integer, 4B aligned).
    {
        const int gbase = (r0s + 8) * GPSTRIDE_W + (52 * qj + 2);
        for (int i = threadIdx.x; i < LWORDS; i += 448) {
            int rr = i / LSTRIDE_W;
            int cc = i - rr * LSTRIDE_W;
            Lw[rr * LSTRIDE_W + cc] = Gp[gbase + rr * GPSTRIDE_W + cc];
        }
    }
    __syncthreads();

    const int d = threadIdx.x;
    if (d < N_DET) {
        const float theta = (float)a * theta_step;
        const float gamma = fmaf((float)d, gstep, -gmax);
        float s1, c1, s2, c2;
        sincosf(theta, &s1, &c1);
        sincosf(theta + gamma, &s2, &c2);
        const float sx = fmaf(1075.0f, c1, 207.5f);
        const float sy = fmaf(1075.0f, s1, 207.5f);

        // col(k) = C0 - k*dc ; row(k) = R0 - k*dr   (k = 0..415)
        const float C0 = fmaf(-t0, c2, sx), dc = dtstep * c2;
        const float R0 = fmaf(-t0, s2, sy), dr = dtstep * s2;

        // tile ownership box, half-open; support of nonzero taps is [-1,416).
        // Inner boundaries use identical fp constants in both neighbors ->
        // exact partition of each ray's samples across tiles.
        const float cl = (qj == 0) ? -1.0f : 104.0f * qj;
        const float ch = (qj == 3) ? 416.0f : 104.0f * (qj + 1);
        const float rl = (qi == 0) ? -1.0f : 208.0f;
        const float rh = (qi == 0) ? 208.0f : 416.0f;

        int klo = 0, khi = N_SAMP - 1;
        auto clip1 = [&](float X0, float dX, float lo, float hi) {
            if (fabsf(dX) < 1e-8f) {
                if (!(X0 >= lo && X0 < hi)) { klo = 1; khi = 0; }
            } else {
                const float inv = 1.0f / dX;
                float x1 = (X0 - hi) * inv;        // strict side
                float x2 = (X0 - lo) * inv;        // inclusive side
                x1 = fminf(fmaxf(x1, -1e6f), 1e6f);
                x2 = fminf(fmaxf(x2, -1e6f), 1e6f);
                int lo_k, hi_k;
                if (dX > 0.0f) { lo_k = (int)floorf(x1) + 1; hi_k = (int)floorf(x2); }
                else           { lo_k = (int)ceilf(x2);      hi_k = (int)ceilf(x1) - 1; }
                klo = max(klo, lo_k);
                khi = min(khi, hi_k);
            }
        };
        clip1(C0, dc, cl, ch);
        clip1(R0, dr, rl, rh);

        if (klo <= khi) {
            // LDS-relative coords (box guarantees >=1.99 -> trunc==floor;
            // march drift <0.01 px absorbed by the 4-px staging margins)
            float colR = fmaf(-(float)klo, dc, C0) - (float)c0s;
            float rowR = fmaf(-(float)klo, dr, R0) - (float)r0s;
            const unsigned short* __restrict__ Lp = (const unsigned short*)Lw;
            float acc = 0.0f;
            #pragma unroll 4
            for (int k = klo; k <= khi; ++k) {
                const int ci = (int)colR;
                const int ri = (int)rowR;
                const float wc = colR - (float)ci;
                const float wr = rowR - (float)ri;
                const int base = ri * LSTRIDE_PX + ci;
                const unsigned int ptop = Lp[base];                 // v00,v01
                const unsigned int pbot = Lp[base + LSTRIDE_PX];    // v10,v11
                const vfloat2 t2 = __builtin_amdgcn_cvt_pk_f32_fp8(ptop, false);
                const vfloat2 b2 = __builtin_amdgcn_cvt_pk_f32_fp8(pbot, false);
                const float top = fmaf(wc, t2[1] - t2[0], t2[0]);
                const float bot = fmaf(wc, b2[1] - b2[0], b2[0]);
                acc = fmaf(wr, bot - top, acc + top);
                colR -= dc;
                rowR -= dr;
            }
            atomicAdd(&S[a * N_DET + d], acc);
        }
    }
}

// ---------------------------------------------------------------------------
// Kernel C: square each ray integral, reduce, scale, one atomic per block.
// ---------------------------------------------------------------------------
__global__ __launch_bounds__(256) void reduce_kernel(const float* __restrict__ S,
                                                     float* __restrict__ out,
                                                     float coef) {
    const int i = blockIdx.x * 256 + threadIdx.x;
    float v = (i < SPLANE) ? S[i] : 0.0f;
    float sq = v * v;
    #pragma unroll
    for (int m = 32; m > 0; m >>= 1) sq += __shfl_down(sq, m, 64);
    __shared__ float w[4];
    const int lane = threadIdx.x & 63;
    if (lane == 0) w[threadIdx.x >> 6] = sq;
    __syncthreads();
    if (threadIdx.x == 0)
        atomicAdd(out, (w[0] + w[1] + w[2] + w[3]) * coef);
}

// ---------------------------------------------------------------------------
// Fallback (ws too small): fused one-thread-per-ray fp32 gather version.
// ---------------------------------------------------------------------------
__global__ __launch_bounds__(256) void proj_fused(const float* __restrict__ imgA,
                                                  const float* __restrict__ imgB,
                                                  float* __restrict__ out,
                                                  float theta_step, float gmax,
                                                  float gstep, float t0,
                                                  float dtstep, float coef) {
    const int idx = blockIdx.x * 256 + threadIdx.x;
    const int a  = idx / N_DET;
    const int dd = idx - a * N_DET;
    const float theta = (float)a * theta_step;
    const float gamma = fmaf((float)dd, gstep, -gmax);
    float s1, c1, s2, c2;
    sincosf(theta, &s1, &c1);
    sincosf(theta + gamma, &s2, &c2);
    const float sx = 1075.0f * c1 + 207.5f;
    const float sy = 1075.0f * s1 + 207.5f;
    float acc = 0.0f;
    #pragma unroll 4
    for (int s = 0; s < N_SAMP; ++s) {
        const float t   = fmaf((float)s, dtstep, t0);
        const float col = fmaf(-t, c2, sx);
        const float row = fmaf(-t, s2, sy);
        const float c0 = floorf(col);
        const float r0 = floorf(row);
        const float wc = col - c0;
        const float wr = row - r0;
        const int ci = (int)c0;
        const int ri = (int)r0;
        auto Gv = [&](int r, int c) -> float {
            if ((unsigned)r < (unsigned)IMG && (unsigned)c < (unsigned)IMG)
                return imgA[r * IMG + c] - imgB[r * IMG + c];
            return 0.0f;
        };
        const float v00 = Gv(ri, ci);
        const float v01 = Gv(ri, ci + 1);
        const float v10 = Gv(ri + 1, ci);
        const float v11 = Gv(ri + 1, ci + 1);
        const float top = fmaf(wc, v01 - v00, v00);
        const float bot = fmaf(wc, v11 - v10, v10);
        acc += fmaf(wr, bot - top, top);
    }
    float sq = acc * acc;
    #pragma unroll
    for (int o = 32; o > 0; o >>= 1) sq += __shfl_down(sq, o, 64);
    __shared__ float wsum[4];
    const int lane = threadIdx.x & 63;
    if (lane == 0) wsum[threadIdx.x >> 6] = sq;
    __syncthreads();
    if (threadIdx.x == 0)
        atomicAdd(out, (wsum[0] + wsum[1] + wsum[2] + wsum[3]) * coef);
}

extern "C" void kernel_launch(void* const* d_in, const int* in_sizes, int n_in,
                              void* d_out, int out_size, void* d_ws, size_t ws_size,
                              hipStream_t stream) {
    const float* in = (const float*)d_in[0];
    const float* tg = (const float*)d_in[1];
    float* out = (float*)d_out;

    const double half_diag = (IMG / 2.0) * sqrt(2.0);
    const double ray_len   = IMG * sqrt(2.0);
    const float  gmax      = (float)asin(half_diag / 1075.0);
    const float  gstep     = (float)(2.0 * (double)gmax / (N_DET - 1));
    const float  t0        = (float)(1075.0 - ray_len / 2.0);
    const float  dtstep    = (float)(ray_len / (N_SAMP - 1));
    const float  theta_step = (float)(2.0 * M_PI / N_ANG);
    const double dt        = ray_len / (N_SAMP - 1);
    const double SCALE     = 512.0 / 416.0 * 0.03;
    const float  coef      = (float)(dt * dt * SCALE / ((double)N_ANG * N_DET));

    if (ws_size >= WSNEED) {
        unsigned int* Gp = (unsigned int*)d_ws;
        float* S = (float*)((char*)d_ws + GPBYTES);
        // grid covers max(GPWORDS, SPLANE): table build + S/out zeroing
        pack_kernel<<<(SPLANE + 255) / 256, 256, 0, stream>>>(in, tg, Gp, S, out);
        proj_lds<<<NBLK, 448, 0, stream>>>(Gp, S, theta_step, gmax, gstep,
                                           t0, dtstep);
        reduce_kernel<<<(SPLANE + 255) / 256, 256, 0, stream>>>(S, out, coef);
    } else {
        zero_out_kernel<<<1, 64, 0, stream>>>(out);
        proj_fused<<<(N_ANG * N_DET) / 256, 256, 0, stream>>>(
            in, tg, out, theta_step, gmax, gstep, t0, dtstep, coef);
    }
}